// Round 8
// baseline (191.969 us; speedup 1.0000x reference)
//
#include <hip/hip_runtime.h>
#include <hip/hip_bf16.h>

typedef __attribute__((ext_vector_type(8))) short bf16x8;
typedef __attribute__((ext_vector_type(4))) float f32x4;
typedef __attribute__((ext_vector_type(4))) unsigned int u32x4;
typedef __attribute__((ext_vector_type(2))) unsigned int u32x2;

#define B_SZ 4
#define C_SZ 256
#define N_SZ 4096
#define DK_SZ 32

// ws layout in bf16 elements
#define WQB_OFF 0
#define WKB_OFF 8192
#define WVB_OFF 16384
#define QB_OFF  81920
#define KB_OFF  606208
#define VB_OFF  1130496

__device__ __forceinline__ short f2bf(float f) {
    union { float f; unsigned int u; } v; v.f = f;
    unsigned int r = v.u + 0x7fffu + ((v.u >> 16) & 1u);
    return (short)(r >> 16);
}

__device__ __forceinline__ float asf(unsigned int u) {
    union { unsigned int u; float f; } v; v.u = u;
    return v.f;
}

__device__ __forceinline__ unsigned int cvt_pk_bf16(float lo, float hi) {
    unsigned int r;
    asm volatile("v_cvt_pk_bf16_f32 %0, %1, %2" : "=v"(r) : "v"(lo), "v"(hi));
    return r;
}

__device__ __forceinline__ f32x4 mfma16(bf16x8 a, bf16x8 b, f32x4 c) {
    return __builtin_amdgcn_mfma_f32_16x16x32_bf16(a, b, c, 0, 0, 0);
}

// XCD-affinity remap: grid = 256 1D, block i -> XCD i%8 (round-robin).
// Batch b owns XCDs {2b, 2b+1} -> per-XCD working set (V_b 2MB + K_b + Q_b) < 4MB L2.
__device__ __forceinline__ void remap_block(int i, int& b, int& n0) {
    b = (i & 7) >> 1;
    n0 = (((i >> 3) << 1) | (i & 1)) * 64;
}

// ---------------- weight conversion ----------------
__global__ __launch_bounds__(256) void k_convw(const float* __restrict__ Wq,
                                               const float* __restrict__ Wk,
                                               const float* __restrict__ Wv,
                                               short* __restrict__ ws) {
    int i = blockIdx.x * 256 + threadIdx.x;
    if (i < 8192) {
        ws[WQB_OFF + i] = f2bf(Wq[i]);
        ws[WKB_OFF + i] = f2bf(Wk[i]);
    }
    ws[WVB_OFF + i] = f2bf(Wv[i]);
}

// ---------------- projection: q, k as [b][n][32] bf16; v as [b][c][n] bf16 ----------------
__global__ __launch_bounds__(256) void k_prep(const float* __restrict__ x,
                                              const float* __restrict__ bq,
                                              const float* __restrict__ bk,
                                              const float* __restrict__ bv,
                                              short* __restrict__ ws) {
    __shared__ short xsT[64][264];
    __shared__ short vt_s[64][258];

    int b, n0;
    remap_block(blockIdx.x, b, n0);
    const int t = threadIdx.x;
    const float* xb = x + (size_t)b * C_SZ * N_SZ;

    {
        int c0 = t >> 4, n4 = (t & 15) * 4;
#pragma unroll
        for (int i = 0; i < 16; i++) {
            int c = c0 + 16 * i;
            float4 v = *(const float4*)(xb + (size_t)c * N_SZ + n0 + n4);
            xsT[n4 + 0][c] = f2bf(v.x);
            xsT[n4 + 1][c] = f2bf(v.y);
            xsT[n4 + 2][c] = f2bf(v.z);
            xsT[n4 + 3][c] = f2bf(v.w);
        }
    }
    __syncthreads();

    const int w = t >> 6, l = t & 63;
    const int lr = l & 15, lk = l >> 4;

    bf16x8 af[8];
#pragma unroll
    for (int kk = 0; kk < 8; kk++)
        af[kk] = *(const bf16x8*)(&xsT[w * 16 + lr][kk * 32 + lk * 8]);

#pragma unroll
    for (int qk = 0; qk < 2; qk++) {
        const short* wb = ws + (qk ? WKB_OFF : WQB_OFF);
        const float* bias = qk ? bk : bq;
        short* outp = ws + (qk ? KB_OFF : QB_OFF) + (size_t)b * N_SZ * DK_SZ;
#pragma unroll
        for (int cf = 0; cf < 2; cf++) {
            f32x4 acc = {0.f, 0.f, 0.f, 0.f};
#pragma unroll
            for (int kk = 0; kk < 8; kk++) {
                bf16x8 bfr = *(const bf16x8*)(wb + (cf * 16 + lr) * 256 + kk * 32 + lk * 8);
                acc = mfma16(af[kk], bfr, acc);
            }
            float bias_v = bias[cf * 16 + lr];
#pragma unroll
            for (int r = 0; r < 4; r++) {
                int row = w * 16 + lk * 4 + r;
                outp[(size_t)(n0 + row) * DK_SZ + cf * 16 + lr] = f2bf(acc[r] + bias_v);
            }
        }
    }

#pragma unroll
    for (int cf = 0; cf < 16; cf++) {
        f32x4 acc = {0.f, 0.f, 0.f, 0.f};
#pragma unroll
        for (int kk = 0; kk < 8; kk++) {
            bf16x8 bfr = *(const bf16x8*)(ws + WVB_OFF + (cf * 16 + lr) * 256 + kk * 32 + lk * 8);
            acc = mfma16(af[kk], bfr, acc);
        }
        float bias_v = bv[cf * 16 + lr];
#pragma unroll
        for (int r = 0; r < 4; r++) {
            vt_s[w * 16 + lk * 4 + r][cf * 16 + lr] = f2bf(acc[r] + bias_v);
        }
    }
    __syncthreads();
    {
        short* vb = ws + VB_OFF + (size_t)b * C_SZ * N_SZ;
        int nn = t & 63;
#pragma unroll
        for (int i = 0; i < 64; i++) {
            int c = (t >> 6) + 4 * i;
            vb[(size_t)c * N_SZ + n0 + nn] = vt_s[nn][c];
        }
    }
}

// ---------------- fused attention (wave-autonomous, zero-barrier main loop) ----------------
// 512 threads = 8 waves. Wave (cq = w&3, mh = w>>2) owns output channels
// [cq*64, cq*64+64) and m-half mh. Per 64-m chunk (32 chunks, NO barriers):
//   - K frags from L2 (4 x b128), swapped QK^T (16 mfma) for ALL 64 n
//   - exp * invp, cvt_pk -> wave-PRIVATE LDS P tile [64][72] (rotation swizzle
//     j' = (j+row)&7 at 16B granularity: all access patterns bank-balanced)
//   - attention rows [cq*16, cq*16+16) stored full-line nontemporal
//   - PV: V A-frags straight from L2 (each V element read by exactly 1 wave),
//     P B-frags from private tile; O[4cf][4rgi] per-m-half partials.
// QK^T+exp are 4x redundant across cq-waves -- the price of zero sync.
// Epilogue: one barrier pair, reduce O across mh-pairs via LDS, residual add.
__global__ __launch_bounds__(512, 1) void k_attn(const short* __restrict__ ws,
                                                 const float* __restrict__ x,
                                                 const float* __restrict__ gamma_p,
                                                 float* __restrict__ out) {
    __shared__ short p_all[8][4608];    // 8 wave-private P tiles [64][72]; 73.7 KB
    __shared__ float rsum_s[2][64];

    int b, n0;
    remap_block(blockIdx.x, b, n0);
    const int t = threadIdx.x, w = t >> 6, l = t & 63;
    const int cq = w & 3, mh = w >> 2;
    const int lr = l & 15, lk = l >> 4;

    const short* qb = ws + QB_OFF + (size_t)b * N_SZ * DK_SZ;
    const short* kb = ws + KB_OFF + (size_t)b * N_SZ * DK_SZ;
    const short* vb = ws + VB_OFF + (size_t)b * C_SZ * N_SZ;

    // ---- pass 1: rowsum of exp(S): wave (cq, mh) does rows cq*16..+16, m-half mh ----
    {
        bf16x8 qf1 = *(const bf16x8*)(qb + (size_t)(n0 + cq * 16 + lr) * DK_SZ + lk * 8);
        float rs = 0.f;
        for (int mt = 0; mt < 32; mt++) {
            int mb = mh * 2048 + mt * 64;
            bf16x8 kfa = *(const bf16x8*)(kb + (size_t)(mb + lr) * DK_SZ + lk * 8);
            bf16x8 kfb = *(const bf16x8*)(kb + (size_t)(mb + 16 + lr) * DK_SZ + lk * 8);
            bf16x8 kfc = *(const bf16x8*)(kb + (size_t)(mb + 32 + lr) * DK_SZ + lk * 8);
            bf16x8 kfd = *(const bf16x8*)(kb + (size_t)(mb + 48 + lr) * DK_SZ + lk * 8);
            f32x4 s0 = mfma16(kfa, qf1, (f32x4){0.f, 0.f, 0.f, 0.f});
            f32x4 s1 = mfma16(kfb, qf1, (f32x4){0.f, 0.f, 0.f, 0.f});
            f32x4 s2 = mfma16(kfc, qf1, (f32x4){0.f, 0.f, 0.f, 0.f});
            f32x4 s3 = mfma16(kfd, qf1, (f32x4){0.f, 0.f, 0.f, 0.f});
#pragma unroll
            for (int r = 0; r < 4; r++)
                rs += __expf(s0[r]) + __expf(s1[r]) + __expf(s2[r]) + __expf(s3[r]);
        }
        rs += __shfl_xor(rs, 16);
        rs += __shfl_xor(rs, 32);
        if (l < 16) rsum_s[mh][cq * 16 + l] = rs;
    }
    __syncthreads();
    float invp4[4];
#pragma unroll
    for (int rg = 0; rg < 4; rg++)
        invp4[rg] = 1.f / (rsum_s[0][rg * 16 + lr] + rsum_s[1][rg * 16 + lr]);

    // Q B-frags for all 4 n-groups
    bf16x8 qfr[4];
#pragma unroll
    for (int rg = 0; rg < 4; rg++)
        qfr[rg] = *(const bf16x8*)(qb + (size_t)(n0 + rg * 16 + lr) * DK_SZ + lk * 8);

    float* attn_b = out + (size_t)B_SZ * C_SZ * N_SZ + (size_t)b * N_SZ * N_SZ;
    short* pw = &p_all[w][0];
    f32x4 O[4][4];   // O[cf][rgi]: c = cq*64+cf*16+4lk+r, n = rgi*16+lr (m-half partial)
#pragma unroll
    for (int cf = 0; cf < 4; cf++)
#pragma unroll
        for (int rgi = 0; rgi < 4; rgi++) O[cf][rgi] = (f32x4){0.f, 0.f, 0.f, 0.f};

    // ---- main loop: 32 chunks of 64 m, fully wave-independent ----
    for (int mc = 0; mc < 32; mc++) {
        const int m0 = mh * 2048 + mc * 64;

        // QK^T + exp + P -> private LDS tile (rotation swizzle per row)
#pragma unroll
        for (int mf = 0; mf < 4; mf++) {
            bf16x8 kf = *(const bf16x8*)(kb + (size_t)(m0 + mf * 16 + lr) * DK_SZ + lk * 8);
#pragma unroll
            for (int rg = 0; rg < 4; rg++) {
                f32x4 s = mfma16(kf, qfr[rg], (f32x4){0.f, 0.f, 0.f, 0.f});
                const float iv = invp4[rg];
                u32x2 pk;
                pk[0] = cvt_pk_bf16(__expf(s[0]) * iv, __expf(s[1]) * iv);
                pk[1] = cvt_pk_bf16(__expf(s[2]) * iv, __expf(s[3]) * iv);
                const int row = rg * 16 + lr;
                const int j = 2 * mf + (lk >> 1);
                *(u32x2*)(pw + row * 72 + (((j + row) & 7) << 3) + 4 * (lk & 1)) = pk;
            }
        }

        // attention store: this wave stores rows [cq*16, cq*16+16), full 128B lines
#pragma unroll
        for (int i = 0; i < 4; i++) {
            const int row = cq * 16 + i * 4 + (l >> 4);
            const int c4 = l & 15;
            const int j = c4 >> 1;
            u32x2 u = *(const u32x2*)(pw + row * 72 + (((j + row) & 7) << 3) + 4 * (c4 & 1));
            f32x4 f;
            f[0] = asf(u[0] << 16); f[1] = asf(u[0] & 0xffff0000u);
            f[2] = asf(u[1] << 16); f[3] = asf(u[1] & 0xffff0000u);
            __builtin_nontemporal_store(f, (f32x4*)(attn_b + (size_t)(n0 + row) * N_SZ + m0 + c4 * 4));
        }

        // PV: A-frags (V) straight from L2, B-frags (P) from private tile
#pragma unroll
        for (int k2 = 0; k2 < 2; k2++) {
            bf16x8 Bf[4], Af[4];
#pragma unroll
            for (int rgi = 0; rgi < 4; rgi++) {
                const int row = rgi * 16 + lr;
                const int j = 4 * k2 + lk;
                Bf[rgi] = *(const bf16x8*)(pw + row * 72 + (((j + row) & 7) << 3));
            }
#pragma unroll
            for (int cf = 0; cf < 4; cf++)
                Af[cf] = *(const bf16x8*)(vb + (size_t)(cq * 64 + cf * 16 + lr) * N_SZ + m0 + k2 * 32 + lk * 8);
#pragma unroll
            for (int cf = 0; cf < 4; cf++)
#pragma unroll
                for (int rgi = 0; rgi < 4; rgi++)
                    O[cf][rgi] = mfma16(Af[cf], Bf[rgi], O[cf][rgi]);
        }
    }

    // ---- epilogue: reduce mh-pairs through LDS, then out = gamma*O + x ----
    __syncthreads();
    float* o_red = (float*)&p_all[0][0];     // [4 n-grp][256 c][16 n], c-stride 17
    const int RSTRIDE = 4360;
    if (mh == 1) {
#pragma unroll
        for (int cf = 0; cf < 4; cf++)
#pragma unroll
            for (int rgi = 0; rgi < 4; rgi++)
#pragma unroll
                for (int r = 0; r < 4; r++)
                    o_red[rgi * RSTRIDE + (cq * 64 + cf * 16 + 4 * lk + r) * 17 + lr] = O[cf][rgi][r];
    }
    __syncthreads();
    if (mh == 0) {
#pragma unroll
        for (int cf = 0; cf < 4; cf++)
#pragma unroll
            for (int rgi = 0; rgi < 4; rgi++)
#pragma unroll
                for (int r = 0; r < 4; r++) {
                    int idx = rgi * RSTRIDE + (cq * 64 + cf * 16 + 4 * lk + r) * 17 + lr;
                    o_red[idx] += O[cf][rgi][r];
                }
    }
    __syncthreads();
    {
        const float g = gamma_p[0];
        const float* xb = x + (size_t)b * C_SZ * N_SZ;
        float* ob = out + (size_t)b * C_SZ * N_SZ;
        int nn = t & 63;
        int c0 = t >> 6;   // 0..7
        int rbase = (nn >> 4) * RSTRIDE + (nn & 15);
#pragma unroll
        for (int i = 0; i < 32; i++) {
            int c = c0 + 8 * i;
            size_t idx = (size_t)c * N_SZ + n0 + nn;
            ob[idx] = g * o_red[rbase + c * 17] + xb[idx];
        }
    }
}

extern "C" void kernel_launch(void* const* d_in, const int* in_sizes, int n_in,
                              void* d_out, int out_size, void* d_ws, size_t ws_size,
                              hipStream_t stream) {
    const float* x     = (const float*)d_in[0];
    const float* Wq    = (const float*)d_in[1];
    const float* bq    = (const float*)d_in[2];
    const float* Wk    = (const float*)d_in[3];
    const float* bk    = (const float*)d_in[4];
    const float* Wv    = (const float*)d_in[5];
    const float* bv    = (const float*)d_in[6];
    const float* gamma = (const float*)d_in[7];
    short* ws = (short*)d_ws;
    float* out = (float*)d_out;

    hipLaunchKernelGGL(k_convw, dim3(256), dim3(256), 0, stream, Wq, Wk, Wv, ws);
    hipLaunchKernelGGL(k_prep, dim3(256), dim3(256), 0, stream, x, bq, bk, bv, ws);
    hipLaunchKernelGGL(k_attn, dim3(256), dim3(512), 0, stream, ws, x, gamma, out);
}

// Round 9
// 187.660 us; speedup vs baseline: 1.0230x; 1.0230x over previous
//
#include <hip/hip_runtime.h>
#include <hip/hip_bf16.h>

typedef __attribute__((ext_vector_type(8))) short bf16x8;
typedef __attribute__((ext_vector_type(4))) float f32x4;
typedef __attribute__((ext_vector_type(4))) unsigned int u32x4;
typedef __attribute__((ext_vector_type(2))) unsigned int u32x2;

#define B_SZ 4
#define C_SZ 256
#define N_SZ 4096
#define DK_SZ 32

// ws layout in bf16 elements
#define WQB_OFF 0
#define WKB_OFF 8192
#define WVB_OFF 16384
#define QB_OFF  81920
#define KB_OFF  606208
#define VB_OFF  1130496

__device__ __forceinline__ short f2bf(float f) {
    union { float f; unsigned int u; } v; v.f = f;
    unsigned int r = v.u + 0x7fffu + ((v.u >> 16) & 1u);
    return (short)(r >> 16);
}

__device__ __forceinline__ float asf(unsigned int u) {
    union { unsigned int u; float f; } v; v.u = u;
    return v.f;
}

__device__ __forceinline__ unsigned int cvt_pk_bf16(float lo, float hi) {
    unsigned int r;
    asm volatile("v_cvt_pk_bf16_f32 %0, %1, %2" : "=v"(r) : "v"(lo), "v"(hi));
    return r;
}

__device__ __forceinline__ f32x4 mfma16(bf16x8 a, bf16x8 b, f32x4 c) {
    return __builtin_amdgcn_mfma_f32_16x16x32_bf16(a, b, c, 0, 0, 0);
}

// XCD-affinity remap (k_prep, grid 256): batch b owns XCDs {2b, 2b+1}.
__device__ __forceinline__ void remap_block(int i, int& b, int& n0) {
    b = (i & 7) >> 1;
    n0 = (((i >> 3) << 1) | (i & 1)) * 64;
}

// ---------------- weight conversion ----------------
__global__ __launch_bounds__(256) void k_convw(const float* __restrict__ Wq,
                                               const float* __restrict__ Wk,
                                               const float* __restrict__ Wv,
                                               short* __restrict__ ws) {
    int i = blockIdx.x * 256 + threadIdx.x;
    if (i < 8192) {
        ws[WQB_OFF + i] = f2bf(Wq[i]);
        ws[WKB_OFF + i] = f2bf(Wk[i]);
    }
    ws[WVB_OFF + i] = f2bf(Wv[i]);
}

// ---------------- projection: q, k as [b][n][32] bf16; v as [b][c][n] bf16 ----------------
__global__ __launch_bounds__(256) void k_prep(const float* __restrict__ x,
                                              const float* __restrict__ bq,
                                              const float* __restrict__ bk,
                                              const float* __restrict__ bv,
                                              short* __restrict__ ws) {
    __shared__ short xsT[64][264];
    __shared__ short vt_s[64][258];

    int b, n0;
    remap_block(blockIdx.x, b, n0);
    const int t = threadIdx.x;
    const float* xb = x + (size_t)b * C_SZ * N_SZ;

    {
        int c0 = t >> 4, n4 = (t & 15) * 4;
#pragma unroll
        for (int i = 0; i < 16; i++) {
            int c = c0 + 16 * i;
            float4 v = *(const float4*)(xb + (size_t)c * N_SZ + n0 + n4);
            xsT[n4 + 0][c] = f2bf(v.x);
            xsT[n4 + 1][c] = f2bf(v.y);
            xsT[n4 + 2][c] = f2bf(v.z);
            xsT[n4 + 3][c] = f2bf(v.w);
        }
    }
    __syncthreads();

    const int w = t >> 6, l = t & 63;
    const int lr = l & 15, lk = l >> 4;

    bf16x8 af[8];
#pragma unroll
    for (int kk = 0; kk < 8; kk++)
        af[kk] = *(const bf16x8*)(&xsT[w * 16 + lr][kk * 32 + lk * 8]);

#pragma unroll
    for (int qk = 0; qk < 2; qk++) {
        const short* wb = ws + (qk ? WKB_OFF : WQB_OFF);
        const float* bias = qk ? bk : bq;
        short* outp = ws + (qk ? KB_OFF : QB_OFF) + (size_t)b * N_SZ * DK_SZ;
#pragma unroll
        for (int cf = 0; cf < 2; cf++) {
            f32x4 acc = {0.f, 0.f, 0.f, 0.f};
#pragma unroll
            for (int kk = 0; kk < 8; kk++) {
                bf16x8 bfr = *(const bf16x8*)(wb + (cf * 16 + lr) * 256 + kk * 32 + lk * 8);
                acc = mfma16(af[kk], bfr, acc);
            }
            float bias_v = bias[cf * 16 + lr];
#pragma unroll
            for (int r = 0; r < 4; r++) {
                int row = w * 16 + lk * 4 + r;
                outp[(size_t)(n0 + row) * DK_SZ + cf * 16 + lr] = f2bf(acc[r] + bias_v);
            }
        }
    }

#pragma unroll
    for (int cf = 0; cf < 16; cf++) {
        f32x4 acc = {0.f, 0.f, 0.f, 0.f};
#pragma unroll
        for (int kk = 0; kk < 8; kk++) {
            bf16x8 bfr = *(const bf16x8*)(ws + WVB_OFF + (cf * 16 + lr) * 256 + kk * 32 + lk * 8);
            acc = mfma16(af[kk], bfr, acc);
        }
        float bias_v = bv[cf * 16 + lr];
#pragma unroll
        for (int r = 0; r < 4; r++) {
            vt_s[w * 16 + lk * 4 + r][cf * 16 + lr] = f2bf(acc[r] + bias_v);
        }
    }
    __syncthreads();
    {
        short* vb = ws + VB_OFF + (size_t)b * C_SZ * N_SZ;
        int nn = t & 63;
#pragma unroll
        for (int i = 0; i < 64; i++) {
            int c = (t >> 6) + 4 * i;
            vb[(size_t)c * N_SZ + n0 + nn] = vt_s[nn][c];
        }
    }
}

// ---------------- fused attention (32-row tiles, 2 blocks/CU, no V/K staging) ----------------
// Grid 512 (2 blocks/CU), 512 threads = 8 waves, 34 KB LDS, VGPR<=128 -> 4 waves/SIMD.
// Counters (r8) showed reads are L2/L3-resident -> K,V read directly (b128 gathers).
// SCOMP mapping: ng=w&1 (16-row n-group), mq=w>>1 (m-16-quarter of the 64-m tile).
// PV mapping:    cq=w&3 (64-channel quarter), mh=w>>2 (m-half) -> O partials.
// Per iter (ONE __syncthreads, no asm): SCOMP(t+1)->p_lds[alt] (1 mfma, 4 exp,
// u32x2 write), ASTORE(t) (full-line nt stores from p_lds[cur]), PV(t) (8 mfma,
// 2 P b128 + 4 V b128-from-L2). Cross-block overlap hides barrier skew + latency.
__global__ __launch_bounds__(512, 4) void k_attn(const short* __restrict__ ws,
                                                 const float* __restrict__ x,
                                                 const float* __restrict__ gamma_p,
                                                 float* __restrict__ out) {
    __shared__ __align__(16) char smem[34816];
    short (*p_lds)[32][72] = (short(*)[32][72])smem;   // [2][32][72] bf16 = 9.2 KB
    float* rsum_s = (float*)(smem + 9216);             // [4][32]

    // 512 blocks: xcd = i&7, batch = (i&7)>>1, within-batch tile 0..127
    const int i = blockIdx.x;
    const int b = (i & 7) >> 1;
    const int n0 = (((i >> 3) << 1) | (i & 1)) * 32;

    const int t = threadIdx.x, w = t >> 6, l = t & 63;
    const int lr = l & 15, lk = l >> 4;
    const int ng = w & 1, mq = w >> 1;   // SCOMP / pass-1
    const int cq = w & 3, mh = w >> 2;   // PV

    const short* qb = ws + QB_OFF + (size_t)b * N_SZ * DK_SZ;
    const short* kb = ws + KB_OFF + (size_t)b * N_SZ * DK_SZ;
    const short* vb = ws + VB_OFF + (size_t)b * C_SZ * N_SZ;

    // Q B-frag for this wave's n-group (held all kernel)
    bf16x8 qf = *(const bf16x8*)(qb + (size_t)(n0 + ng * 16 + lr) * DK_SZ + lk * 8);

    // ---- pass 1: rowsum of exp(S); wave (ng, mq) covers m-quarter mq ----
    float rs = 0.f;
    for (int mt = 0; mt < 16; mt++) {
        int mb = mq * 1024 + mt * 64;
        bf16x8 kfa = *(const bf16x8*)(kb + (size_t)(mb + lr) * DK_SZ + lk * 8);
        bf16x8 kfb = *(const bf16x8*)(kb + (size_t)(mb + 16 + lr) * DK_SZ + lk * 8);
        bf16x8 kfc = *(const bf16x8*)(kb + (size_t)(mb + 32 + lr) * DK_SZ + lk * 8);
        bf16x8 kfd = *(const bf16x8*)(kb + (size_t)(mb + 48 + lr) * DK_SZ + lk * 8);
        f32x4 s0 = mfma16(kfa, qf, (f32x4){0.f, 0.f, 0.f, 0.f});
        f32x4 s1 = mfma16(kfb, qf, (f32x4){0.f, 0.f, 0.f, 0.f});
        f32x4 s2 = mfma16(kfc, qf, (f32x4){0.f, 0.f, 0.f, 0.f});
        f32x4 s3 = mfma16(kfd, qf, (f32x4){0.f, 0.f, 0.f, 0.f});
#pragma unroll
        for (int r = 0; r < 4; r++)
            rs += __expf(s0[r]) + __expf(s1[r]) + __expf(s2[r]) + __expf(s3[r]);
    }
    rs += __shfl_xor(rs, 16);
    rs += __shfl_xor(rs, 32);
    if (l < 16) rsum_s[mq * 32 + ng * 16 + l] = rs;
    __syncthreads();
    const float invp = 1.f / (rsum_s[ng * 16 + lr] + rsum_s[32 + ng * 16 + lr] +
                              rsum_s[64 + ng * 16 + lr] + rsum_s[96 + ng * 16 + lr]);

    float* attn_b = out + (size_t)B_SZ * C_SZ * N_SZ + (size_t)b * N_SZ * N_SZ;
    f32x4 O[4][2];   // O[cf][rgi]: c = cq*64+cf*16+4lk+r, n = rgi*16+lr (m-half partial)
#pragma unroll
    for (int cf = 0; cf < 4; cf++)
#pragma unroll
        for (int rgi = 0; rgi < 2; rgi++) O[cf][rgi] = (f32x4){0.f, 0.f, 0.f, 0.f};

    // SCOMP(tt): one 16x16 S-tile per wave -> exp*invp -> p_lds[pb]
#define SCOMP(tt, pb)                                                               \
    {                                                                               \
        bf16x8 kf = *(const bf16x8*)(kb + (size_t)((tt) * 64 + mq * 16 + lr) * DK_SZ + lk * 8); \
        f32x4 s = mfma16(kf, qf, (f32x4){0.f, 0.f, 0.f, 0.f});                      \
        u32x2 pk;                                                                   \
        pk[0] = cvt_pk_bf16(__expf(s[0]) * invp, __expf(s[1]) * invp);              \
        pk[1] = cvt_pk_bf16(__expf(s[2]) * invp, __expf(s[3]) * invp);              \
        *(u32x2*)(&p_lds[pb][ng * 16 + lr][mq * 16 + lk * 4]) = pk;                 \
    }

    // ASTORE(tt): full-line nt stores; thread t -> row t>>4, m-chunk (t&15)*4
#define ASTORE(tt, pb)                                                              \
    {                                                                               \
        const int arow = t >> 4;                                                    \
        const int m16 = t & 15;                                                     \
        u32x2 u = *(const u32x2*)(&p_lds[pb][arow][m16 * 4]);                       \
        f32x4 f;                                                                    \
        f[0] = asf(u[0] << 16); f[1] = asf(u[0] & 0xffff0000u);                     \
        f[2] = asf(u[1] << 16); f[3] = asf(u[1] & 0xffff0000u);                     \
        __builtin_nontemporal_store(f,                                              \
            (f32x4*)(attn_b + (size_t)(n0 + arow) * N_SZ + (tt) * 64 + m16 * 4));   \
    }

    // PV(tt): O[c-quarter][2 n-grp] += V-frags (L2) * P-frags (p_lds[pb])
#define PV(tt, pb)                                                                  \
    {                                                                               \
        bf16x8 Bf[2], Af[4];                                                        \
        _Pragma("unroll")                                                           \
        for (int rgi = 0; rgi < 2; rgi++)                                           \
            Bf[rgi] = *(const bf16x8*)((const char*)&p_lds[pb][rgi * 16 + lr][0]    \
                                       + mh * 64 + lk * 16);                        \
        _Pragma("unroll")                                                           \
        for (int cf = 0; cf < 4; cf++)                                              \
            Af[cf] = *(const bf16x8*)(vb + (size_t)(cq * 64 + cf * 16 + lr) * N_SZ  \
                                      + (tt) * 64 + mh * 32 + lk * 8);              \
        _Pragma("unroll")                                                           \
        for (int cf = 0; cf < 4; cf++)                                              \
            _Pragma("unroll")                                                       \
            for (int rgi = 0; rgi < 2; rgi++)                                       \
                O[cf][rgi] = mfma16(Af[cf], Bf[rgi], O[cf][rgi]);                   \
    }

    SCOMP(0, 0);
    for (int mt = 0; mt < 64; mt++) {
        __syncthreads();
        const int cur = mt & 1;
        if (mt < 63) SCOMP(mt + 1, cur ^ 1);
        ASTORE(mt, cur);
        PV(mt, cur);
    }
#undef SCOMP
#undef ASTORE
#undef PV

    // ---- epilogue: reduce mh-pairs through LDS, then out = gamma*O + x ----
    __syncthreads();
    float* o_red = (float*)smem;    // [256 c][32 n], c-stride 33 -> 33.8 KB
    if (mh == 1) {
#pragma unroll
        for (int cf = 0; cf < 4; cf++)
#pragma unroll
            for (int rgi = 0; rgi < 2; rgi++)
#pragma unroll
                for (int r = 0; r < 4; r++)
                    o_red[(cq * 64 + cf * 16 + 4 * lk + r) * 33 + rgi * 16 + lr] = O[cf][rgi][r];
    }
    __syncthreads();
    if (mh == 0) {
#pragma unroll
        for (int cf = 0; cf < 4; cf++)
#pragma unroll
            for (int rgi = 0; rgi < 2; rgi++)
#pragma unroll
                for (int r = 0; r < 4; r++)
                    o_red[(cq * 64 + cf * 16 + 4 * lk + r) * 33 + rgi * 16 + lr] += O[cf][rgi][r];
    }
    __syncthreads();
    {
        const float g = gamma_p[0];
        const float* xb = x + (size_t)b * C_SZ * N_SZ;
        float* ob = out + (size_t)b * C_SZ * N_SZ;
        int nn = t & 31;
        int c0 = t >> 5;   // 0..15
#pragma unroll
        for (int i2 = 0; i2 < 16; i2++) {
            int c = c0 + 16 * i2;
            size_t idx = (size_t)c * N_SZ + n0 + nn;
            ob[idx] = g * o_red[c * 33 + nn] + xb[idx];
        }
    }
}

extern "C" void kernel_launch(void* const* d_in, const int* in_sizes, int n_in,
                              void* d_out, int out_size, void* d_ws, size_t ws_size,
                              hipStream_t stream) {
    const float* x     = (const float*)d_in[0];
    const float* Wq    = (const float*)d_in[1];
    const float* bq    = (const float*)d_in[2];
    const float* Wk    = (const float*)d_in[3];
    const float* bk    = (const float*)d_in[4];
    const float* Wv    = (const float*)d_in[5];
    const float* bv    = (const float*)d_in[6];
    const float* gamma = (const float*)d_in[7];
    short* ws = (short*)d_ws;
    float* out = (float*)d_out;

    hipLaunchKernelGGL(k_convw, dim3(256), dim3(256), 0, stream, Wq, Wk, Wv, ws);
    hipLaunchKernelGGL(k_prep, dim3(256), dim3(256), 0, stream, x, bq, bk, bv, ws);
    hipLaunchKernelGGL(k_attn, dim3(512), dim3(512), 0, stream, ws, x, gamma, out);
}